// Round 7
// baseline (437.998 us; speedup 1.0000x reference)
//
#include <hip/hip_runtime.h>

typedef _Float16 h8_t __attribute__((ext_vector_type(8)));
typedef _Float16 h4_t __attribute__((ext_vector_type(4)));
typedef __fp16 fp16x2 __attribute__((ext_vector_type(2)));
typedef float f32x4 __attribute__((ext_vector_type(4)));

#define NB 64
#define NH 8
#define NL 2048
#define ND 512
// flat K matrix rows: NB*NL = 131072

// ---------------- Kernel 1: Wq = Q @ Ww.T + Wb  (f32, tiny) ----------------
__global__ __launch_bounds__(256) void wq_kernel(const float* __restrict__ Q,
                                                 const float* __restrict__ Ww,
                                                 const float* __restrict__ Wb,
                                                 float* __restrict__ Wq) {
    __shared__ float q[ND];
    const int b = blockIdx.x;
    const int t = threadIdx.x;
    for (int i = t; i < ND; i += 256) q[i] = Q[b * ND + i];
    __syncthreads();
    for (int j = t; j < ND; j += 256) {
        const float* wr = Ww + (size_t)j * ND;
        float acc = 0.f;
        for (int k = 0; k < ND; k += 4) {
            float4 w = *(const float4*)(wr + k);
            acc += q[k] * w.x + q[k + 1] * w.y + q[k + 2] * w.z + q[k + 3] * w.w;
        }
        Wq[b * ND + j] = acc + Wb[j];
    }
}

// ---------------- Kernel 2: convert Uw (f32) -> fp16 (RNE) ----------------
__global__ __launch_bounds__(256) void cvt_uw_kernel(const float* __restrict__ Uw,
                                                     _Float16* __restrict__ UwH) {
    const size_t i = ((size_t)blockIdx.x * 256 + threadIdx.x) * 4;
    float4 v = *(const float4*)(Uw + i);
    h4_t h = {(_Float16)v.x, (_Float16)v.y, (_Float16)v.z, (_Float16)v.w};
    *(h4_t*)(UwH + i) = h;
}

// ---------------- Kernel 3: Uk GEMM (fp16 MFMA) + tanh-reduce -> scores ----------------
// NO LDS, NO BARRIERS. BM=256 (4 waves m-split, wave tile 64x64), BN=64, grid 4096.
// A fragments loaded per-lane from global f32 (cvt_pkrtz in reg); B per-lane from
// L2-resident UwH fp16. Compiler pipelines loads across fully-unrolled K with
// counted vmcnt -- no barrier to defeat it. Waves fully independent.
// bid decode puts all 8 n-twins of an m-panel on one XCD (A L2-hot re-reads):
//   xcd = tm&7:  bid = (tm&7) + 8*((tm>>3)*8 + nb)
__global__ __launch_bounds__(256, 4) void uk_score_kernel(
    const float* __restrict__ Km,       // [131072][512] f32
    const _Float16* __restrict__ UwH,   // [512][512] fp16
    const float* __restrict__ Ub,       // [512]
    const float* __restrict__ Wq,       // [64][512]
    const float* __restrict__ Vw,       // [64]
    const float* __restrict__ Vb,       // [1]
    float* __restrict__ scores)         // [512][2048]
{
    const int t = threadIdx.x;
    const int lane = t & 63;
    const int w = t >> 6;             // 0..3: m-split wave id
    const int col16 = lane & 15;
    const int kg = lane >> 4;         // 0..3

    const int bid = blockIdx.x;       // 4096
    const int nb = (bid >> 3) & 7;                 // 0..7  (n-chunk = score jb)
    const int tm = ((bid >> 6) << 3) | (bid & 7);  // 0..511 (m-panel of 256 rows)
    const size_t row0 = (size_t)tm * 256;
    const int n0 = nb * 64;

    // per-lane fragment base pointers (all 16 K-steps reachable via imm offsets)
    const float* gA[4];
#pragma unroll
    for (int i = 0; i < 4; ++i)
        gA[i] = Km + (row0 + w * 64 + i * 16 + col16) * (size_t)ND + kg * 8;
    const _Float16* gB[4];
#pragma unroll
    for (int j = 0; j < 4; ++j)
        gB[j] = UwH + (size_t)(n0 + j * 16 + col16) * ND + kg * 8;

    f32x4 acc[4][4];
#pragma unroll
    for (int i = 0; i < 4; ++i)
#pragma unroll
        for (int j = 0; j < 4; ++j) acc[i][j] = (f32x4){0.f, 0.f, 0.f, 0.f};

#pragma unroll
    for (int s = 0; s < 16; ++s) {
        h8_t bf[4];
#pragma unroll
        for (int j = 0; j < 4; ++j)
            bf[j] = *(const h8_t*)(gB[j] + s * 32);
        h8_t af[4];
#pragma unroll
        for (int i = 0; i < 4; ++i) {
            f32x4 a0 = *(const f32x4*)(gA[i] + s * 32);
            f32x4 a1 = *(const f32x4*)(gA[i] + s * 32 + 4);
            union { h8_t h8; fp16x2 h2[4]; } u;
            u.h2[0] = __builtin_amdgcn_cvt_pkrtz(a0[0], a0[1]);
            u.h2[1] = __builtin_amdgcn_cvt_pkrtz(a0[2], a0[3]);
            u.h2[2] = __builtin_amdgcn_cvt_pkrtz(a1[0], a1[1]);
            u.h2[3] = __builtin_amdgcn_cvt_pkrtz(a1[2], a1[3]);
            af[i] = u.h8;
        }
#pragma unroll
        for (int i = 0; i < 4; ++i)
#pragma unroll
            for (int j = 0; j < 4; ++j)
                acc[i][j] = __builtin_amdgcn_mfma_f32_16x16x32_f16(af[i], bf[j], acc[i][j], 0, 0, 0);
    }

    // epilogue: score(row, nb) = sum_dh tanh(Uk + Wq + Ub) * Vw  (+Vb)
    // block is (b,h)-pure: b = tm>>3, h = tm&7, bh = tm
    const int b = tm >> 3;
    const int h = tm & 7;

    float vw[4], wqv[4], ubv[4];
#pragma unroll
    for (int j = 0; j < 4; ++j) {
        const int dh = j * 16 + col16;            // 0..63
        vw[j] = Vw[dh];
        wqv[j] = Wq[b * ND + h * 64 + dh];
        ubv[j] = Ub[n0 + dh];
    }
    const float vb0 = Vb[0];

#pragma unroll
    for (int i = 0; i < 4; ++i) {
#pragma unroll
        for (int r = 0; r < 4; ++r) {
            float s = 0.f;
#pragma unroll
            for (int j = 0; j < 4; ++j) {
                float x = acc[i][j][r] + wqv[j] + ubv[j];
                x = fminf(fmaxf(x, -15.f), 15.f);
                float e = __expf(2.f * x);
                // tanh = 1 - 2/(e+1)
                s += (1.f - 2.f * __builtin_amdgcn_rcpf(e + 1.f)) * vw[j];
            }
#pragma unroll
            for (int o = 8; o >= 1; o >>= 1) s += __shfl_xor(s, o);
            if (col16 == 0) {
                const int rloc = w * 64 + i * 16 + kg * 4 + r;   // 0..255
                scores[(size_t)tm * NL + rloc * 8 + nb] = s + vb0;
            }
        }
    }
}

// ---------------- Kernel 4: softmax -> dist (out) + attn = dist @ Kh ----------------
__global__ __launch_bounds__(256) void softmax_attn_kernel(
    const float* __restrict__ Km,
    const float* __restrict__ scores,
    float* __restrict__ out)  // [0,32768) attn, [32768,...) dist
{
    __shared__ float sd[NL];
    __shared__ float red[256];
    __shared__ float att[16][64];

    const int bh = blockIdx.x;
    const int b = bh >> 3, h = bh & 7;
    const int t = threadIdx.x;

    float loc[8];
    float mx = -1e30f;
#pragma unroll
    for (int j = 0; j < 8; ++j) {
        loc[j] = scores[(size_t)bh * NL + j * 256 + t];
        mx = fmaxf(mx, loc[j]);
    }
    red[t] = mx;
    __syncthreads();
    for (int s2 = 128; s2 > 0; s2 >>= 1) {
        if (t < s2) red[t] = fmaxf(red[t], red[t + s2]);
        __syncthreads();
    }
    mx = red[0];
    __syncthreads();
    float sum = 0.f;
#pragma unroll
    for (int j = 0; j < 8; ++j) {
        loc[j] = __expf(loc[j] - mx);
        sum += loc[j];
    }
    red[t] = sum;
    __syncthreads();
    for (int s2 = 128; s2 > 0; s2 >>= 1) {
        if (t < s2) red[t] += red[t + s2];
        __syncthreads();
    }
    const float inv = 1.f / red[0];
    __syncthreads();

    float* dist_out = out + 32768 + (size_t)bh * NL;
#pragma unroll
    for (int j = 0; j < 8; ++j) {
        float d = loc[j] * inv;
        sd[j * 256 + t] = d;
        dist_out[j * 256 + t] = d;
    }
    __syncthreads();

    const int wave = t >> 6, lane = t & 63;
    const int g = lane >> 4;
    const int c4 = (lane & 15) * 4;
    f32x4 acc = (f32x4){0.f, 0.f, 0.f, 0.f};
    const float* kb = Km + ((size_t)b * NL + h * 256) * ND;
    for (int rr = 0; rr < 16; ++rr) {
        const int row = wave * 64 + rr * 4 + g;
        const float* kr = kb + (size_t)row * ND;
#pragma unroll
        for (int jb2 = 0; jb2 < 8; ++jb2) {
            const float w = sd[row * 8 + jb2];
            float4 v = *(const float4*)(kr + jb2 * 64 + c4);
            acc[0] += w * v.x;
            acc[1] += w * v.y;
            acc[2] += w * v.z;
            acc[3] += w * v.w;
        }
    }
    *(f32x4*)&att[wave * 4 + g][c4] = acc;
    __syncthreads();
    if (t < 64) {
        float a = 0.f;
#pragma unroll
        for (int i = 0; i < 16; ++i) a += att[i][t];
        out[(size_t)b * ND + h * 64 + t] = a;
    }
}

extern "C" void kernel_launch(void* const* d_in, const int* in_sizes, int n_in,
                              void* d_out, int out_size, void* d_ws, size_t ws_size,
                              hipStream_t stream) {
    const float* Q  = (const float*)d_in[0];
    const float* Km = (const float*)d_in[1];
    const float* Ww = (const float*)d_in[2];
    const float* Wb = (const float*)d_in[3];
    const float* Uw = (const float*)d_in[4];
    const float* Ub = (const float*)d_in[5];
    const float* Vw = (const float*)d_in[6];
    const float* Vb = (const float*)d_in[7];
    float* out = (float*)d_out;

    char* ws = (char*)d_ws;
    float* scores = (float*)ws;                              // 4 MB
    float* Wq = (float*)(ws + 4194304);                      // 128 KB
    _Float16* UwH = (_Float16*)(ws + 4194304 + 131072);      // 512 KB

    wq_kernel<<<dim3(64), dim3(256), 0, stream>>>(Q, Ww, Wb, Wq);
    cvt_uw_kernel<<<dim3(256), dim3(256), 0, stream>>>(Uw, UwH);
    uk_score_kernel<<<dim3(4096), dim3(256), 0, stream>>>(Km, UwH, Ub, Wq, Vw, Vb, scores);
    softmax_attn_kernel<<<dim3(512), dim3(256), 0, stream>>>(Km, scores, out);
}

// Round 8
// 195.863 us; speedup vs baseline: 2.2362x; 2.2362x over previous
//
#include <hip/hip_runtime.h>

typedef _Float16 h8_t __attribute__((ext_vector_type(8)));
typedef _Float16 h4_t __attribute__((ext_vector_type(4)));
typedef float f32x4 __attribute__((ext_vector_type(4)));

#define NB 64
#define NH 8
#define NL 2048
#define ND 512
// flat K matrix rows: NB*NL = 131072

#define GLD_LDS16(g, l) \
    __builtin_amdgcn_global_load_lds((const __attribute__((address_space(1))) unsigned int*)(g), \
                                     (__attribute__((address_space(3))) unsigned int*)(l), 16, 0, 0)
#define SBAR() __builtin_amdgcn_sched_barrier(0)

// swizzled half-index into a [rows][32]-fp16 tile: XOR 16B-chunk with row bits
__device__ __forceinline__ int swz_idx(int row, int chunk) {
    return row * 32 + ((chunk ^ ((row >> 1) & 3)) << 3);
}

// ---------------- Kernel 1: Wq = Q @ Ww.T + Wb  (f32, tiny) ----------------
__global__ __launch_bounds__(256) void wq_kernel(const float* __restrict__ Q,
                                                 const float* __restrict__ Ww,
                                                 const float* __restrict__ Wb,
                                                 float* __restrict__ Wq) {
    __shared__ float q[ND];
    const int b = blockIdx.x;
    const int t = threadIdx.x;
    for (int i = t; i < ND; i += 256) q[i] = Q[b * ND + i];
    __syncthreads();
    for (int j = t; j < ND; j += 256) {
        const float* wr = Ww + (size_t)j * ND;
        float acc = 0.f;
        for (int k = 0; k < ND; k += 4) {
            float4 w = *(const float4*)(wr + k);
            acc += q[k] * w.x + q[k + 1] * w.y + q[k + 2] * w.z + q[k + 3] * w.w;
        }
        Wq[b * ND + j] = acc + Wb[j];
    }
}

// ---------------- Kernel 2: convert Uw (f32) -> fp16 (RNE) ----------------
__global__ __launch_bounds__(256) void cvt_uw_kernel(const float* __restrict__ Uw,
                                                     _Float16* __restrict__ UwH) {
    const size_t i = ((size_t)blockIdx.x * 256 + threadIdx.x) * 4;
    float4 v = *(const float4*)(Uw + i);
    h4_t h = {(_Float16)v.x, (_Float16)v.y, (_Float16)v.z, (_Float16)v.w};
    *(h4_t*)(UwH + i) = h;
}

// ---------------- Kernel 3: Uk GEMM (fp16 MFMA) + tanh-reduce -> scores ----------------
// BM=128, BN=256, BK=32, 8 waves (2m x 4n). R2 structure + TRUE pipelining:
// raw s_barrier + counted vmcnt(2) -- A(s+2) reg-loads stay in flight ACROSS the
// barrier (full iteration of HBM-latency cover); B(s+1) gload_lds gets a full
// iteration of L2 cover. vmem queue order pinned by sched_barrier(0):
//   [A(s+1) (iter s-1), B(s+1) (iter s-1, post-barrier), A(s+2) (iter s)]
// so vmcnt(2) drains exactly A(s+1)+B(s+1) and leaves A(s+2) flying.
__global__ __launch_bounds__(512, 4) void uk_score_kernel(
    const float* __restrict__ Km,       // [131072][512] f32
    const _Float16* __restrict__ UwH,   // [512][512] fp16
    const float* __restrict__ Ub,       // [512]
    const float* __restrict__ Wq,       // [64][512]
    const float* __restrict__ Vw,       // [64]
    const float* __restrict__ Vb,       // [1]
    float* __restrict__ scores)         // [512][2048]
{
    __shared__ __align__(16) _Float16 Al[2][128 * 32];   // 2 x 8 KB
    __shared__ __align__(16) _Float16 Bl[2][256 * 32];   // 2 x 16 KB

    const int t = threadIdx.x;
    const int lane = t & 63;
    const int wave = t >> 6;          // 0..7
    const int wm = wave >> 2;         // 0..1
    const int wn = wave & 3;          // 0..3

    const int bid = blockIdx.x;                      // 2048 blocks
    const int swz = (bid & 7) * 256 + (bid >> 3);    // bijective XCD swizzle
    const int tn = swz & 1;
    const int tm = swz >> 1;                         // 0..1023
    const size_t row0 = (size_t)tm * 128;
    const int n0 = tn * 256;

    f32x4 acc[4][4];
#pragma unroll
    for (int i = 0; i < 4; ++i)
#pragma unroll
        for (int j = 0; j < 4; ++j) acc[i][j] = (f32x4){0.f, 0.f, 0.f, 0.f};

    // A staging: thread t loads 8 consecutive floats of row (t>>2), chunk (t&3)
    const int arow = t >> 2;
    const int achunk = t & 3;
    const float* gA = Km + (row0 + arow) * (size_t)ND + achunk * 8;
    const int a_dst = swz_idx(arow, achunk);

    // B staging (global_load_lds, source pre-swizzled)
    const int brow0 = t >> 2;
    const int bc0 = (t & 3) ^ ((brow0 >> 1) & 3);
    const int brow1 = (512 + t) >> 2;
    const int bc1 = (t & 3) ^ ((brow1 >> 1) & 3);
    const _Float16* gB0 = UwH + (size_t)(n0 + brow0) * ND + bc0 * 8;
    const _Float16* gB1 = UwH + (size_t)(n0 + brow1) * ND + bc1 * 8;
    const int bdst0 = (t & ~63) * 16;
    const int bdst1 = (512 + (t & ~63)) * 16;

    const int col16 = lane & 15;
    const int kg = lane >> 4;

    float4 rA[2][2];   // A reg-staging slots; iter s loads A(s+2) into slot[s&1]

    // ---- prologue ----
    {
        float4 p0 = *(const float4*)(gA);        // A(0), consumed immediately
        float4 p1 = *(const float4*)(gA + 4);
        SBAR();
        GLD_LDS16(gB0, (char*)Bl[0] + bdst0);    // B(0)
        GLD_LDS16(gB1, (char*)Bl[0] + bdst1);
        SBAR();
        rA[1][0] = *(const float4*)(gA + 32);    // A(1) -> slot 1
        rA[1][1] = *(const float4*)(gA + 36);
        SBAR();
        h8_t ah = {(_Float16)p0.x, (_Float16)p0.y, (_Float16)p0.z, (_Float16)p0.w,
                   (_Float16)p1.x, (_Float16)p1.y, (_Float16)p1.z, (_Float16)p1.w};
        *(h8_t*)&Al[0][a_dst] = ah;              // compiler drains A(0) here
    }
    asm volatile("s_waitcnt vmcnt(2)" ::: "memory");   // B(0) landed; A(1) flying
    asm volatile("s_waitcnt lgkmcnt(0)" ::: "memory");
    SBAR();
    __builtin_amdgcn_s_barrier();
    SBAR();
    GLD_LDS16(gB0 + 32, (char*)Bl[1] + bdst0);   // B(1)
    GLD_LDS16(gB1 + 32, (char*)Bl[1] + bdst1);
    SBAR();

#pragma unroll
    for (int s = 0; s < 16; ++s) {
        const int cur = s & 1;
        // phase 1: issue A(s+2) reg loads (queue: A(s+1), B(s+1), A(s+2))
        if (s <= 13) {
            rA[cur][0] = *(const float4*)(gA + (s + 2) * 32);
            rA[cur][1] = *(const float4*)(gA + (s + 2) * 32 + 4);
        }
        SBAR();
        // phase 2: fragment ds_reads from current buffers
        h8_t af[4], bf[4];
#pragma unroll
        for (int i = 0; i < 4; ++i)
            af[i] = *(const h8_t*)&Al[cur][swz_idx(wm * 64 + i * 16 + col16, kg)];
#pragma unroll
        for (int j = 0; j < 4; ++j)
            bf[j] = *(const h8_t*)&Bl[cur][swz_idx(wn * 64 + j * 16 + col16, kg)];
        asm volatile("s_waitcnt lgkmcnt(0)" ::: "memory");
        SBAR();
        // phase 3: MFMA
#pragma unroll
        for (int i = 0; i < 4; ++i)
#pragma unroll
            for (int j = 0; j < 4; ++j)
                acc[i][j] = __builtin_amdgcn_mfma_f32_16x16x32_f16(af[i], bf[j], acc[i][j], 0, 0, 0);
        SBAR();
        if (s <= 14) {
            // phase 4: counted drain -- A(s+1)+B(s+1) done, A(s+2) stays in flight
            if (s == 14) { asm volatile("s_waitcnt vmcnt(0)" ::: "memory"); }
            else         { asm volatile("s_waitcnt vmcnt(2)" ::: "memory"); }
            SBAR();
            // phase 5: cvt A(s+1) (loaded at iter s-1, slot cur^1) -> bufA[nxt]
            const float4 q0 = rA[cur ^ 1][0];
            const float4 q1 = rA[cur ^ 1][1];
            h8_t ah = {(_Float16)q0.x, (_Float16)q0.y, (_Float16)q0.z, (_Float16)q0.w,
                       (_Float16)q1.x, (_Float16)q1.y, (_Float16)q1.z, (_Float16)q1.w};
            *(h8_t*)&Al[cur ^ 1][a_dst] = ah;
            asm volatile("s_waitcnt lgkmcnt(0)" ::: "memory");
            SBAR();
            // phase 6: barrier (no vmem drain!)
            __builtin_amdgcn_s_barrier();
            SBAR();
            // phase 7: B(s+2) into the buffer all waves just finished reading
            if (s <= 13) {
                GLD_LDS16(gB0 + (s + 2) * 32, (char*)Bl[cur] + bdst0);
                GLD_LDS16(gB1 + (s + 2) * 32, (char*)Bl[cur] + bdst1);
            }
            SBAR();
        }
    }

    // epilogue: score(row, jb) = sum_dh tanh(Uk + Wq + Ub) * Vw  (+Vb)
    const int b = (int)(row0 >> 11);
    const int h = ((int)row0 >> 8) & 7;
    const int i256b = (int)row0 & 255;

    float vw[4], wqv[4], ubv[4];
#pragma unroll
    for (int j = 0; j < 4; ++j) {
        const int jglob = n0 + wn * 64 + j * 16 + col16;  // 0..511
        const int dh = jglob & 63;
        vw[j] = Vw[dh];
        wqv[j] = Wq[b * ND + h * 64 + dh];
        ubv[j] = Ub[jglob];
    }
    const float vb0 = Vb[0];
    const int jb = tn * 4 + wn;       // 0..7
    const int bh = b * 8 + h;

#pragma unroll
    for (int i = 0; i < 4; ++i) {
#pragma unroll
        for (int r = 0; r < 4; ++r) {
            float s = 0.f;
#pragma unroll
            for (int j = 0; j < 4; ++j) {
                float x = acc[i][j][r] + wqv[j] + ubv[j];
                x = fminf(fmaxf(x, -15.f), 15.f);
                float e = __expf(2.f * x);
                s += ((e - 1.f) / (e + 1.f)) * vw[j];
            }
#pragma unroll
            for (int o = 8; o >= 1; o >>= 1) s += __shfl_xor(s, o);
            if (col16 == 0) {
                const int rloc = wm * 64 + i * 16 + kg * 4 + r;
                const int m = (i256b + rloc) * 8 + jb;
                scores[(size_t)bh * NL + m] = s + vb0;
            }
        }
    }
}

// ---------------- Kernel 4: softmax -> dist (out) + attn = dist @ Kh ----------------
__global__ __launch_bounds__(256) void softmax_attn_kernel(
    const float* __restrict__ Km,
    const float* __restrict__ scores,
    float* __restrict__ out)  // [0,32768) attn, [32768,...) dist
{
    __shared__ float sd[NL];
    __shared__ float red[256];
    __shared__ float att[16][64];

    const int bh = blockIdx.x;
    const int b = bh >> 3, h = bh & 7;
    const int t = threadIdx.x;

    float loc[8];
    float mx = -1e30f;
#pragma unroll
    for (int j = 0; j < 8; ++j) {
        loc[j] = scores[(size_t)bh * NL + j * 256 + t];
        mx = fmaxf(mx, loc[j]);
    }
    red[t] = mx;
    __syncthreads();
    for (int s2 = 128; s2 > 0; s2 >>= 1) {
        if (t < s2) red[t] = fmaxf(red[t], red[t + s2]);
        __syncthreads();
    }
    mx = red[0];
    __syncthreads();
    float sum = 0.f;
#pragma unroll
    for (int j = 0; j < 8; ++j) {
        loc[j] = __expf(loc[j] - mx);
        sum += loc[j];
    }
    red[t] = sum;
    __syncthreads();
    for (int s2 = 128; s2 > 0; s2 >>= 1) {
        if (t < s2) red[t] += red[t + s2];
        __syncthreads();
    }
    const float inv = 1.f / red[0];
    __syncthreads();

    float* dist_out = out + 32768 + (size_t)bh * NL;
#pragma unroll
    for (int j = 0; j < 8; ++j) {
        float d = loc[j] * inv;
        sd[j * 256 + t] = d;
        dist_out[j * 256 + t] = d;
    }
    __syncthreads();

    const int wave = t >> 6, lane = t & 63;
    const int g = lane >> 4;
    const int c4 = (lane & 15) * 4;
    f32x4 acc = (f32x4){0.f, 0.f, 0.f, 0.f};
    const float* kb = Km + ((size_t)b * NL + h * 256) * ND;
    for (int rr = 0; rr < 16; ++rr) {
        const int row = wave * 64 + rr * 4 + g;
        const float* kr = kb + (size_t)row * ND;
#pragma unroll
        for (int jb2 = 0; jb2 < 8; ++jb2) {
            const float w = sd[row * 8 + jb2];
            float4 v = *(const float4*)(kr + jb2 * 64 + c4);
            acc[0] += w * v.x;
            acc[1] += w * v.y;
            acc[2] += w * v.z;
            acc[3] += w * v.w;
        }
    }
    *(f32x4*)&att[wave * 4 + g][c4] = acc;
    __syncthreads();
    if (t < 64) {
        float a = 0.f;
#pragma unroll
        for (int i = 0; i < 16; ++i) a += att[i][t];
        out[(size_t)b * ND + h * 64 + t] = a;
    }
}

extern "C" void kernel_launch(void* const* d_in, const int* in_sizes, int n_in,
                              void* d_out, int out_size, void* d_ws, size_t ws_size,
                              hipStream_t stream) {
    const float* Q  = (const float*)d_in[0];
    const float* Km = (const float*)d_in[1];
    const float* Ww = (const float*)d_in[2];
    const float* Wb = (const float*)d_in[3];
    const float* Uw = (const float*)d_in[4];
    const float* Ub = (const float*)d_in[5];
    const float* Vw = (const float*)d_in[6];
    const float* Vb = (const float*)d_in[7];
    float* out = (float*)d_out;

    char* ws = (char*)d_ws;
    float* scores = (float*)ws;                              // 4 MB
    float* Wq = (float*)(ws + 4194304);                      // 128 KB
    _Float16* UwH = (_Float16*)(ws + 4194304 + 131072);      // 512 KB

    wq_kernel<<<dim3(64), dim3(256), 0, stream>>>(Q, Ww, Wb, Wq);
    cvt_uw_kernel<<<dim3(256), dim3(256), 0, stream>>>(Uw, UwH);
    uk_score_kernel<<<dim3(2048), dim3(512), 0, stream>>>(Km, UwH, Ub, Wq, Vw, Vb, scores);
    softmax_attn_kernel<<<dim3(512), dim3(256), 0, stream>>>(Km, scores, out);
}